// Round 7
// baseline (17214.386 us; speedup 1.0000x reference)
//
#include <hip/hip_runtime.h>
#include <hip/hip_bf16.h>

// Problem constants
#define B_ 128
#define T_ 1024
#define D_ 512
#define H_ 256
#define G_ 1024   // 4*H

typedef __bf16 bf16_t;
typedef __bf16 bf16x8 __attribute__((ext_vector_type(8)));
typedef __bf16 bf16x4 __attribute__((ext_vector_type(4)));
typedef float  f32x4  __attribute__((ext_vector_type(4)));

__device__ __forceinline__ float fast_rcp(float x) { return __builtin_amdgcn_rcpf(x); }

__device__ __forceinline__ float sigmoid_f(float x) {
  return fast_rcp(1.0f + __expf(-x));
}
__device__ __forceinline__ float tanh_f(float x) {
  x = fminf(fmaxf(x, -15.0f), 15.0f);   // avoid inf/inf NaN
  float e = __expf(-2.0f * x);
  return (1.0f - e) * fast_rcp(1.0f + e);
}

// Workgroup barrier that waits only on LDS ops (lgkmcnt).
__device__ __forceinline__ void barrier_lds_only() {
  asm volatile("s_waitcnt lgkmcnt(0)\n\ts_barrier" ::: "memory");
}

// global -> LDS direct copy, 16B per lane.
__device__ __forceinline__ void gload_lds16(const void* g, void* l) {
  __builtin_amdgcn_global_load_lds(
      (const __attribute__((address_space(1))) void*)g,
      (__attribute__((address_space(3))) void*)l, 16, 0, 0);
}

// ---------------------------------------------------------------------------
// prep (slow path): W_hh fp32 -> bf16, bias = b_ih + b_hh
// ---------------------------------------------------------------------------
__global__ __launch_bounds__(256) void prep_kernel(
    const float* __restrict__ Whh, const float* __restrict__ bih,
    const float* __restrict__ bhh, bf16_t* __restrict__ whhb,
    float* __restrict__ bias) {
  int i = blockIdx.x * 256 + threadIdx.x;
  if (i < G_ * H_) whhb[i] = (bf16_t)Whh[i];
  if (i < G_) bias[i] = bih[i] + bhh[i];
}

// prep (fast path): also W_ih fp32 -> bf16. Grid 2048x256 = G_*D_.
__global__ __launch_bounds__(256) void prep_full_kernel(
    const float* __restrict__ Whh, const float* __restrict__ bih,
    const float* __restrict__ bhh, const float* __restrict__ Wih,
    bf16_t* __restrict__ whhb, bf16_t* __restrict__ wihb,
    float* __restrict__ bias) {
  int i = blockIdx.x * 256 + threadIdx.x;
  if (i < G_ * H_) whhb[i] = (bf16_t)Whh[i];
  wihb[i] = (bf16_t)Wih[i];
  if (i < G_) bias[i] = bih[i] + bhh[i];
}

// ---------------------------------------------------------------------------
// X fp32 [B,T,D] -> bf16 (fast path only).
// ---------------------------------------------------------------------------
__global__ __launch_bounds__(256) void xconv_kernel(
    const float* __restrict__ X, bf16_t* __restrict__ Xb) {
  const int n4 = (B_ * T_ * D_) / 4;
  const int stride = gridDim.x * 256;
  for (int i = blockIdx.x * 256 + threadIdx.x; i < n4; i += stride) {
    float4 v = ((const float4*)X)[i];
    ((bf16x4*)Xb)[i] =
        (bf16x4){(bf16_t)v.x, (bf16_t)v.y, (bf16_t)v.z, (bf16_t)v.w};
  }
}

// ---------------------------------------------------------------------------
// zero the h exchange buffers (both parities, 128 KB) + sync counter
// ---------------------------------------------------------------------------
__global__ __launch_bounds__(256) void hinit_kernel(
    unsigned* __restrict__ hg32, unsigned* __restrict__ ctr) {
  int i = blockIdx.x * 256 + threadIdx.x;
  if (i < 32768) hg32[i] = 0u;
  if (i == 0) *ctr = 0u;
}

// ---------------------------------------------------------------------------
// FAST xg_gemm (round-5 verified): bf16 inputs, global_load_lds staging,
// 2x4 wave grid, XOR bank-swizzle both sides.
// ---------------------------------------------------------------------------
__global__ __launch_bounds__(512) void xg_gemm_fast(
    const bf16_t* __restrict__ Xb, const bf16_t* __restrict__ Wihb,
    const float* __restrict__ bias, bf16_t* __restrict__ xg2) {
  __shared__ __align__(16) bf16_t As[128][64];
  __shared__ __align__(16) bf16_t Bs[256][64];

  const int tid = threadIdx.x;
  const int lane = tid & 63;
  const int w = tid >> 6;
  const int wm = w >> 2;
  const int wn = w & 3;
  const int q = lane >> 4;
  const int l15 = lane & 15;
  const int m0 = blockIdx.x * 128;
  const int ch0 = blockIdx.y * 64;

  const int lr = lane >> 3;
  const int ls = (lane & 7) ^ (lr & 7);
  const int lc = ls * 8;

  f32x4 acc[4][4];
  #pragma unroll
  for (int mi = 0; mi < 4; ++mi)
    #pragma unroll
    for (int nf = 0; nf < 4; ++nf) acc[mi][nf] = (f32x4){0.f, 0.f, 0.f, 0.f};

  const char* As0 = (const char*)&As[0][0];
  const char* Bs0 = (const char*)&Bs[0][0];

  for (int kt = 0; kt < 8; ++kt) {
    const int k0 = kt * 64;
    __syncthreads();
    #pragma unroll
    for (int j = 0; j < 2; ++j) {
      const int c = w * 2 + j;
      gload_lds16(Xb + (size_t)(m0 + c * 8 + lr) * D_ + k0 + lc,
                  (char*)&As[0][0] + c * 1024);
    }
    #pragma unroll
    for (int j = 0; j < 4; ++j) {
      const int c = w * 4 + j;
      const int br = c * 8 + lr;
      const int wr = (br >> 6) * 256 + ch0 + (br & 63);
      gload_lds16(Wihb + (size_t)wr * D_ + k0 + lc,
                  (char*)&Bs[0][0] + c * 1024);
    }
    __syncthreads();
    #pragma unroll
    for (int kk = 0; kk < 2; ++kk) {
      bf16x8 a[4], b[4];
      #pragma unroll
      for (int mi = 0; mi < 4; ++mi) {
        const int row = wm * 64 + mi * 16 + l15;
        a[mi] = *(const bf16x8*)(As0 + row * 128 +
                                 (((kk * 4 + q) ^ (row & 7)) * 16));
      }
      #pragma unroll
      for (int nf = 0; nf < 4; ++nf) {
        const int row = nf * 64 + wn * 16 + l15;
        b[nf] = *(const bf16x8*)(Bs0 + row * 128 +
                                 (((kk * 4 + q) ^ (row & 7)) * 16));
      }
      #pragma unroll
      for (int mi = 0; mi < 4; ++mi)
        #pragma unroll
        for (int nf = 0; nf < 4; ++nf)
          acc[mi][nf] =
              __builtin_amdgcn_mfma_f32_16x16x32_bf16(a[mi], b[nf], acc[mi][nf], 0, 0, 0);
    }
  }
  const int cc = ch0 + wn * 16 + l15;
  const float bv0 = bias[cc], bv1 = bias[256 + cc];
  const float bv2 = bias[512 + cc], bv3 = bias[768 + cc];
  #pragma unroll
  for (int mi = 0; mi < 4; ++mi) {
    #pragma unroll
    for (int i = 0; i < 4; ++i) {
      const int row = m0 + wm * 64 + mi * 16 + 4 * q + i;
      bf16x4 v = (bf16x4){(bf16_t)(acc[mi][0][i] + bv0), (bf16_t)(acc[mi][1][i] + bv1),
                          (bf16_t)(acc[mi][2][i] + bv2), (bf16_t)(acc[mi][3][i] + bv3)};
      *(bf16x4*)(xg2 + ((size_t)row * 256 + cc) * 4) = v;
    }
  }
}

// ---------------------------------------------------------------------------
// SLOW xg_gemm (fallback): fp32 inputs, VALU staging.
// ---------------------------------------------------------------------------
__global__ __launch_bounds__(512) void xg_gemm(
    const float* __restrict__ X, const float* __restrict__ Wih,
    const float* __restrict__ bias, bf16_t* __restrict__ xg2) {
  __shared__ __align__(16) bf16_t As[128][72];
  __shared__ __align__(16) bf16_t Bs[256][72];

  const int tid = threadIdx.x;
  const int lane = tid & 63;
  const int w = tid >> 6;
  const int q = lane >> 4;
  const int l15 = lane & 15;
  const int m0 = blockIdx.x * 128;
  const int ch0 = blockIdx.y * 64;

  f32x4 acc[16];
  #pragma unroll
  for (int n = 0; n < 16; ++n) acc[n] = (f32x4){0.f, 0.f, 0.f, 0.f};

  for (int kt = 0; kt < 8; ++kt) {
    const int k0 = kt * 64;
    __syncthreads();
    #pragma unroll
    for (int i = 0; i < 4; ++i) {
      int f = tid + 512 * i;
      int r = f >> 4, c4 = f & 15;
      float4 va = *(const float4*)(X + (size_t)(m0 + r) * D_ + k0 + c4 * 4);
      *(bf16x4*)&As[r][c4 * 4] =
          (bf16x4){(bf16_t)va.x, (bf16_t)va.y, (bf16_t)va.z, (bf16_t)va.w};
    }
    #pragma unroll
    for (int j = 0; j < 8; ++j) {
      int f = tid + 512 * j;
      int r = f >> 4, c4 = f & 15;
      int wr = (r >> 6) * 256 + ch0 + (r & 63);
      float4 vb = *(const float4*)(Wih + (size_t)wr * D_ + k0 + c4 * 4);
      *(bf16x4*)&Bs[r][c4 * 4] =
          (bf16x4){(bf16_t)vb.x, (bf16_t)vb.y, (bf16_t)vb.z, (bf16_t)vb.w};
    }
    __syncthreads();
    #pragma unroll
    for (int kk = 0; kk < 2; ++kk) {
      bf16x8 a = *(const bf16x8*)&As[16 * w + l15][kk * 32 + q * 8];
      #pragma unroll
      for (int n = 0; n < 16; ++n) {
        bf16x8 b = *(const bf16x8*)&Bs[16 * n + l15][kk * 32 + q * 8];
        acc[n] = __builtin_amdgcn_mfma_f32_16x16x32_bf16(a, b, acc[n], 0, 0, 0);
      }
    }
  }
  #pragma unroll
  for (int cs = 0; cs < 4; ++cs) {
    const int cc = ch0 + cs * 16 + l15;
    float bv0 = bias[cc], bv1 = bias[256 + cc];
    float bv2 = bias[512 + cc], bv3 = bias[768 + cc];
    #pragma unroll
    for (int i = 0; i < 4; ++i) {
      int row = m0 + 16 * w + 4 * q + i;
      bf16x4 v = (bf16x4){(bf16_t)(acc[cs][i] + bv0), (bf16_t)(acc[4 + cs][i] + bv1),
                          (bf16_t)(acc[8 + cs][i] + bv2), (bf16_t)(acc[12 + cs][i] + bv3)};
      *(bf16x4*)(xg2 + ((size_t)row * 256 + cc) * 4) = v;
    }
  }
}

// ---------------------------------------------------------------------------
// NEW LSTM scan: 32 WGs x 512 thr. WG w owns 8 channels x 4 gates (32 W_hh
// rows, 16 KB -> 64 VGPR/wave). Per step: gates[128 batch x 32 rows], M=128
// fully used -> 16 MFMA/wave (vs 64), ~1/4 VALU/lane, zero LDS.
// h [2][128][256] bf16 exchanged via global: plain stores -> __threadfence
// (agent release) -> atomicAdd ctr -> leader spins (acquire).
// HANG-PROOF: spin is bounded by a pure ITERATION CAP (no clock64) — a
// protocol bug yields a wrong answer + full counters, never a hung container.
// ---------------------------------------------------------------------------
__global__ __launch_bounds__(512) void lstm_scan_gx(
    const bf16_t* __restrict__ xg2, const bf16_t* __restrict__ whhb,
    bf16_t* __restrict__ hg, unsigned* __restrict__ ctr,
    float* __restrict__ hT) {
  const int tid = threadIdx.x;
  const int lane = tid & 63;
  const int w = tid >> 6;              // wave 0..7 -> batch rows 16w..16w+15
  const int q = lane >> 4;
  const int l15 = lane & 15;
  const int ch_base = blockIdx.x * 8;  // this WG's 8 channels
  const bool low = (l15 < 8);
  const int ch = ch_base + (l15 & 7);
  const int b0 = 16 * w + 4 * q + (low ? 0 : 2);

  // ---- W_hh slice -> registers: 16 bf16x8 frags (64 VGPR) ----
  const int gA = (l15 >> 3);           // n=0: gate i / f
  const int gB = 2 + (l15 >> 3);       // n=1: gate g / o
  bf16x8 wb0[8], wb1[8];
  #pragma unroll
  for (int kk = 0; kk < 8; ++kk) {
    wb0[kk] = *(const bf16x8*)(whhb + ((size_t)gA * 256 + ch) * 256 + kk * 32 + q * 8);
    wb1[kk] = *(const bf16x8*)(whhb + ((size_t)gB * 256 + ch) * 256 + kk * 32 + q * 8);
  }

  bf16_t* hP[2] = {hg, hg + 128 * 256};
  const bf16_t* ha = hg + ((size_t)(16 * w + l15) * 256 + q * 8);  // parity-0 a-frag base

  float cst[2] = {0.f, 0.f};

  // xg pointers for the 2 cells; elem = (b*T + t)*1024 + ch*4
  const bf16_t* xp0 = xg2 + (size_t)b0 * T_ * 1024 + ch * 4;
  const bf16_t* xp1 = xg2 + (size_t)(b0 + 1) * T_ * 1024 + ch * 4;
  bf16x4 xv0 = *(const bf16x4*)xp0, xv1 = *(const bf16x4*)xp1;
  xp0 += 1024; xp1 += 1024;

  for (int t = 0; t < T_; ++t) {
    const int cur = t & 1;
    // prefetch xg for t+1 (overruns at t=1023 land in whhb region, unused)
    bf16x4 xn0 = *(const bf16x4*)xp0;
    bf16x4 xn1 = *(const bf16x4*)xp1;
    xp0 += 1024; xp1 += 1024;

    // ---- gates = h @ Whh_slice^T ----
    const bf16_t* hb = ha + (cur ? 128 * 256 : 0);
    f32x4 acc0 = (f32x4){0.f, 0.f, 0.f, 0.f};
    f32x4 acc1 = (f32x4){0.f, 0.f, 0.f, 0.f};
    #pragma unroll
    for (int kk = 0; kk < 8; ++kk) {
      bf16x8 af = *(const bf16x8*)(hb + kk * 32);
      acc0 = __builtin_amdgcn_mfma_f32_16x16x32_bf16(af, wb0[kk], acc0, 0, 0, 0);
      acc1 = __builtin_amdgcn_mfma_f32_16x16x32_bf16(af, wb1[kk], acc1, 0, 0, 0);
    }

    // ---- redistribute across lane pair l15 <-> l15+8 ----
    float tA0 = __shfl_xor(acc0[0], 8, 64), tA1 = __shfl_xor(acc0[1], 8, 64);
    float tA2 = __shfl_xor(acc0[2], 8, 64), tA3 = __shfl_xor(acc0[3], 8, 64);
    float tB0 = __shfl_xor(acc1[0], 8, 64), tB1 = __shfl_xor(acc1[1], 8, 64);
    float tB2 = __shfl_xor(acc1[2], 8, 64), tB3 = __shfl_xor(acc1[3], 8, 64);

    float fi0 = low ? acc0[0] : tA2, fi1 = low ? acc0[1] : tA3;
    float ff0 = low ? tA0 : acc0[2], ff1 = low ? tA1 : acc0[3];
    float fg0 = low ? acc1[0] : tB2, fg1 = low ? acc1[1] : tB3;
    float fo0 = low ? tB0 : acc1[2], fo1 = low ? tB1 : acc1[3];

    // ---- 2 cell updates ----
    float gi0 = fi0 + (float)xv0[0], gf0 = ff0 + (float)xv0[1];
    float gg0 = fg0 + (float)xv0[2], go0 = fo0 + (float)xv0[3];
    float I0 = sigmoid_f(gi0), F0 = sigmoid_f(gf0);
    float G0 = tanh_f(gg0), O0 = sigmoid_f(go0);
    float cv0 = F0 * cst[0] + I0 * G0; cst[0] = cv0;
    float hv0 = O0 * tanh_f(cv0);

    float gi1 = fi1 + (float)xv1[0], gf1 = ff1 + (float)xv1[1];
    float gg1 = fg1 + (float)xv1[2], go1 = fo1 + (float)xv1[3];
    float I1 = sigmoid_f(gi1), F1 = sigmoid_f(gf1);
    float G1 = tanh_f(gg1), O1 = sigmoid_f(go1);
    float cv1 = F1 * cst[1] + I1 * G1; cst[1] = cv1;
    float hv1 = O1 * tanh_f(cv1);

    // ---- pack + store h_next (one u32 per lane, coalesced per ch-pair) ----
    unsigned short h0b = __builtin_bit_cast(unsigned short, (bf16_t)hv0);
    unsigned short h1b = __builtin_bit_cast(unsigned short, (bf16_t)hv1);
    unsigned p = (unsigned)h0b | ((unsigned)h1b << 16);
    unsigned sh = (unsigned)__shfl_xor((int)p, 1, 64);
    unsigned val = (ch & 1) ? ((sh >> 16) | (p & 0xFFFF0000u))
                            : ((p & 0xFFFFu) | (sh << 16));
    int brow = (ch & 1) ? (b0 + 1) : b0;
    *((unsigned*)hP[cur ^ 1] + brow * 128 + (ch >> 1)) = val;

    if (t == T_ - 1) {
      hT[(size_t)b0 * H_ + ch] = hv0;
      hT[(size_t)(b0 + 1) * H_ + ch] = hv1;
    }

    xv0 = xn0; xv1 = xn1;

    // ---- cross-WG step sync: release -> count -> bounded spin -> acquire ----
    __threadfence();                       // agent release: flush h stores
    __syncthreads();                       // all waves of WG done
    if (tid == 0) {
      __hip_atomic_fetch_add(ctr, 1u, __ATOMIC_RELAXED, __HIP_MEMORY_SCOPE_AGENT);
      const unsigned target = 32u * (unsigned)(t + 1);
      unsigned spin = 0;
      while (__hip_atomic_load(ctr, __ATOMIC_RELAXED, __HIP_MEMORY_SCOPE_AGENT) < target) {
        __builtin_amdgcn_s_sleep(2);
        if (++spin > 10000u) break;        // bounded: wrong answer, never a hang
      }
    }
    __syncthreads();
    __threadfence();                       // agent acquire: fresh h reads
  }
}

// ---------------------------------------------------------------------------
// OLD LSTM scan (fallback, verified): 16 WGs x 8 batch rows, 8 waves/WG.
// ---------------------------------------------------------------------------
__global__ __launch_bounds__(512, 2) void lstm_scan(
    const bf16_t* __restrict__ xg2, const bf16_t* __restrict__ Whh,
    float* __restrict__ hT) {
  __shared__ __align__(16) bf16_t wlds[8 * 16 * 512];   // 128 KB
  __shared__ __align__(16) bf16_t hbuf[2][16][264];     // 16.9 KB

  const int tid = threadIdx.x;
  const int lane = tid & 63;
  const int w = tid >> 6;
  const int q = lane >> 4;
  const int l15 = lane & 15;
  const int b0 = blockIdx.x * 8;
  const int rq = (q & 1) * 4 + (q >> 1) * 2;
  const bool hi = (lane >= 32);

  bf16x8 wreg[6][8];
  #pragma unroll
  for (int p2 = 0; p2 < 2; ++p2) {
    #pragma unroll
    for (int g2 = 0; g2 < 4; ++g2) {
      const int j = p2 * 4 + g2;
      const bf16_t* src =
          Whh + (size_t)(g2 * 256 + 32 * w + 16 * p2 + l15) * H_ + q * 8;
      #pragma unroll
      for (int kk = 0; kk < 8; ++kk) {
        bf16x8 v = *(const bf16x8*)(src + kk * 32);
        if (j < 6) {
          wreg[j][kk] = v;
        } else {
          *(bf16x8*)&wlds[(size_t)((w * 16 + (g2 - 2) * 8 + kk)) * 512 + lane * 8] = v;
        }
      }
    }
  }

  for (int i = tid; i < 2 * 16 * 264; i += 512) ((bf16_t*)hbuf)[i] = (bf16_t)0.0f;
  __syncthreads();

  float cst[2][2];
  #pragma unroll
  for (int p = 0; p < 2; ++p) { cst[p][0] = 0.f; cst[p][1] = 0.f; }

  const bf16_t* xp[2][2];
  #pragma unroll
  for (int p = 0; p < 2; ++p)
    #pragma unroll
    for (int k = 0; k < 2; ++k)
      xp[p][k] = xg2 + (size_t)(b0 + rq + k) * (size_t)T_ * 1024 + (32 * w + 16 * p + l15) * 4;

  bf16x4 xv[2][2], xn[2][2];
  #pragma unroll
  for (int p = 0; p < 2; ++p)
    #pragma unroll
    for (int k = 0; k < 2; ++k) {
      xv[p][k] = *(const bf16x4*)xp[p][k];
      xp[p][k] += 1024;
    }

  auto step = [&](int t, bf16x4 (&xc)[2][2], bf16x4 (&xf)[2][2]) {
    #pragma unroll
    for (int p = 0; p < 2; ++p)
      #pragma unroll
      for (int k = 0; k < 2; ++k) {
        xf[p][k] = *(const bf16x4*)xp[p][k];
        xp[p][k] += 1024;
      }
    const int cur = t & 1;
    #pragma unroll
    for (int p = 0; p < 2; ++p) {
      f32x4 acc[4];
      #pragma unroll
      for (int g = 0; g < 4; ++g) acc[g] = (f32x4){0.f, 0.f, 0.f, 0.f};
      #pragma unroll
      for (int kk = 0; kk < 8; ++kk) {
        bf16x8 a = *(const bf16x8*)&hbuf[cur][l15][kk * 32 + q * 8];
        if (p == 0) {
          acc[0] = __builtin_amdgcn_mfma_f32_16x16x32_bf16(a, wreg[0][kk], acc[0], 0, 0, 0);
          acc[1] = __builtin_amdgcn_mfma_f32_16x16x32_bf16(a, wreg[1][kk], acc[1], 0, 0, 0);
          acc[2] = __builtin_amdgcn_mfma_f32_16x16x32_bf16(a, wreg[2][kk], acc[2], 0, 0, 0);
          acc[3] = __builtin_amdgcn_mfma_f32_16x16x32_bf16(a, wreg[3][kk], acc[3], 0, 0, 0);
        } else {
          acc[0] = __builtin_amdgcn_mfma_f32_16x16x32_bf16(a, wreg[4][kk], acc[0], 0, 0, 0);
          acc[1] = __builtin_amdgcn_mfma_f32_16x16x32_bf16(a, wreg[5][kk], acc[1], 0, 0, 0);
          bf16x8 bg = *(const bf16x8*)&wlds[(size_t)(w * 16 + kk) * 512 + lane * 8];
          bf16x8 bo = *(const bf16x8*)&wlds[(size_t)(w * 16 + 8 + kk) * 512 + lane * 8];
          acc[2] = __builtin_amdgcn_mfma_f32_16x16x32_bf16(a, bg, acc[2], 0, 0, 0);
          acc[3] = __builtin_amdgcn_mfma_f32_16x16x32_bf16(a, bo, acc[3], 0, 0, 0);
        }
      }
      float G0[4], G1[4];
      #pragma unroll
      for (int g = 0; g < 4; ++g) {
        float s2 = __shfl(acc[g][2], lane ^ 32, 64);
        float s3 = __shfl(acc[g][3], lane ^ 32, 64);
        G0[g] = hi ? s2 : acc[g][0];
        G1[g] = hi ? s3 : acc[g][1];
      }
      const int c = 32 * w + 16 * p + l15;
      #pragma unroll
      for (int k = 0; k < 2; ++k) {
        const float* Gv_ = k ? G1 : G0;
        float gi = Gv_[0] + (float)xc[p][k][0];
        float gf = Gv_[1] + (float)xc[p][k][1];
        float gg = Gv_[2] + (float)xc[p][k][2];
        float go = Gv_[3] + (float)xc[p][k][3];
        float I = sigmoid_f(gi);
        float F = sigmoid_f(gf);
        float Gg = tanh_f(gg);
        float Ov = sigmoid_f(go);
        float cv = F * cst[p][k] + I * Gg;
        cst[p][k] = cv;
        float hv = Ov * tanh_f(cv);
        hbuf[cur ^ 1][rq + k][c] = (bf16_t)hv;
        if (t == T_ - 1) hT[(size_t)(b0 + rq + k) * H_ + c] = hv;
      }
    }
    barrier_lds_only();
  };

  #pragma unroll 1
  for (int t = 0; t < T_; t += 2) {
    step(t, xv, xn);
    step(t + 1, xn, xv);
  }
}

// ---------------------------------------------------------------------------
// out = h_T @ W_out^T + b_out
// ---------------------------------------------------------------------------
__global__ __launch_bounds__(128) void head_gemm(
    const float* __restrict__ hT, const float* __restrict__ Wout,
    const float* __restrict__ bout, float* __restrict__ out) {
  __shared__ float hrow[H_];
  const int b = blockIdx.x;
  const int o = threadIdx.x;
  hrow[o] = hT[(size_t)b * H_ + o];
  hrow[o + 128] = hT[(size_t)b * H_ + 128 + o];
  __syncthreads();
  float s = bout[o];
  const float* wr = Wout + (size_t)o * H_;
  #pragma unroll 8
  for (int j = 0; j < H_; ++j) s += hrow[j] * wr[j];
  out[(size_t)b * 128 + o] = s;
}

// ---------------------------------------------------------------------------
extern "C" void kernel_launch(void* const* d_in, const int* in_sizes, int n_in,
                              void* d_out, int out_size, void* d_ws, size_t ws_size,
                              hipStream_t stream) {
  const float* X    = (const float*)d_in[0];
  const float* Wih  = (const float*)d_in[1];
  const float* Whh  = (const float*)d_in[2];
  const float* bih  = (const float*)d_in[3];
  const float* bhh  = (const float*)d_in[4];
  const float* Wout = (const float*)d_in[5];
  const float* bout = (const float*)d_in[6];
  float* out = (float*)d_out;

  // workspace layout (bytes). Prefix byte-identical to the proven layout.
  // hg/ctr REUSE the wihb region (1 MB; wihb is dead after xg_gemm_fast).
  char* ws = (char*)d_ws;
  const size_t XG_BYTES   = (size_t)B_ * T_ * G_ * 2;   // 268435456
  const size_t WHHB_BYTES = (size_t)G_ * H_ * 2;        // 524288
  const size_t BIAS_BYTES = (size_t)G_ * 4;             // 4096
  const size_t HT_BYTES   = (size_t)B_ * H_ * 4;        // 131072
  const size_t WIHB_BYTES = (size_t)G_ * D_ * 2;        // 1048576
  const size_t XB_BYTES   = (size_t)B_ * T_ * D_ * 2;   // 134217728
  bf16_t* xg2  = (bf16_t*)ws;
  bf16_t* whhb = (bf16_t*)(ws + XG_BYTES);
  float*  bias = (float*)(ws + XG_BYTES + WHHB_BYTES);
  float*  hT   = (float*)(ws + XG_BYTES + WHHB_BYTES + BIAS_BYTES);
  bf16_t* wihb = (bf16_t*)(ws + XG_BYTES + WHHB_BYTES + BIAS_BYTES + HT_BYTES);
  bf16_t* xb   = (bf16_t*)(ws + XG_BYTES + WHHB_BYTES + BIAS_BYTES + HT_BYTES + WIHB_BYTES);
  bf16_t* hg   = wihb;                                   // 2*128*256 bf16 = 128 KB
  unsigned* ctr = (unsigned*)(wihb + 2 * 128 * 256);     // +4 B, inside wihb's 1 MB

  const size_t NEED_FAST =
      XG_BYTES + WHHB_BYTES + BIAS_BYTES + HT_BYTES + WIHB_BYTES + XB_BYTES;

  if (ws_size >= NEED_FAST) {
    prep_full_kernel<<<dim3(2048), 256, 0, stream>>>(Whh, bih, bhh, Wih, whhb, wihb, bias);
    xconv_kernel<<<dim3(4096), 256, 0, stream>>>(X, xb);
    xg_gemm_fast<<<dim3((B_ * T_) / 128, 4), 512, 0, stream>>>(xb, wihb, bias, xg2);
    hinit_kernel<<<dim3(128), 256, 0, stream>>>((unsigned*)hg, ctr);
    lstm_scan_gx<<<dim3(32), 512, 0, stream>>>(xg2, whhb, hg, ctr, hT);
  } else {
    prep_kernel<<<dim3(1024), 256, 0, stream>>>(Whh, bih, bhh, whhb, bias);
    xg_gemm<<<dim3((B_ * T_) / 128, 4), 512, 0, stream>>>(X, Wih, bias, xg2);
    lstm_scan<<<dim3(B_ / 8), 512, 0, stream>>>(xg2, whhb, hT);
  }
  head_gemm<<<dim3(B_), 128, 0, stream>>>(hT, Wout, bout, out);
}

// Round 8
// 5996.360 us; speedup vs baseline: 2.8708x; 2.8708x over previous
//
#include <hip/hip_runtime.h>
#include <hip/hip_bf16.h>

// Problem constants
#define B_ 128
#define T_ 1024
#define D_ 512
#define H_ 256
#define G_ 1024   // 4*H

typedef __bf16 bf16_t;
typedef __bf16 bf16x8 __attribute__((ext_vector_type(8)));
typedef __bf16 bf16x4 __attribute__((ext_vector_type(4)));
typedef float  f32x4  __attribute__((ext_vector_type(4)));

__device__ __forceinline__ float fast_rcp(float x) { return __builtin_amdgcn_rcpf(x); }

__device__ __forceinline__ float sigmoid_f(float x) {
  return fast_rcp(1.0f + __expf(-x));
}
__device__ __forceinline__ float tanh_f(float x) {
  x = fminf(fmaxf(x, -15.0f), 15.0f);   // avoid inf/inf NaN
  float e = __expf(-2.0f * x);
  return (1.0f - e) * fast_rcp(1.0f + e);
}

// Workgroup barrier that waits only on LDS ops (lgkmcnt).
__device__ __forceinline__ void barrier_lds_only() {
  asm volatile("s_waitcnt lgkmcnt(0)\n\ts_barrier" ::: "memory");
}

// global -> LDS direct copy, 16B per lane.
__device__ __forceinline__ void gload_lds16(const void* g, void* l) {
  __builtin_amdgcn_global_load_lds(
      (const __attribute__((address_space(1))) void*)g,
      (__attribute__((address_space(3))) void*)l, 16, 0, 0);
}

// ---------------------------------------------------------------------------
// prep (slow path): W_hh fp32 -> bf16, bias = b_ih + b_hh
// ---------------------------------------------------------------------------
__global__ __launch_bounds__(256) void prep_kernel(
    const float* __restrict__ Whh, const float* __restrict__ bih,
    const float* __restrict__ bhh, bf16_t* __restrict__ whhb,
    float* __restrict__ bias) {
  int i = blockIdx.x * 256 + threadIdx.x;
  if (i < G_ * H_) whhb[i] = (bf16_t)Whh[i];
  if (i < G_) bias[i] = bih[i] + bhh[i];
}

// prep (fast path): also W_ih fp32 -> bf16. Grid 2048x256 = G_*D_.
__global__ __launch_bounds__(256) void prep_full_kernel(
    const float* __restrict__ Whh, const float* __restrict__ bih,
    const float* __restrict__ bhh, const float* __restrict__ Wih,
    bf16_t* __restrict__ whhb, bf16_t* __restrict__ wihb,
    float* __restrict__ bias) {
  int i = blockIdx.x * 256 + threadIdx.x;
  if (i < G_ * H_) whhb[i] = (bf16_t)Whh[i];
  wihb[i] = (bf16_t)Wih[i];
  if (i < G_) bias[i] = bih[i] + bhh[i];
}

// ---------------------------------------------------------------------------
// X fp32 [B,T,D] -> bf16 (fast path only).
// ---------------------------------------------------------------------------
__global__ __launch_bounds__(256) void xconv_kernel(
    const float* __restrict__ X, bf16_t* __restrict__ Xb) {
  const int n4 = (B_ * T_ * D_) / 4;
  const int stride = gridDim.x * 256;
  for (int i = blockIdx.x * 256 + threadIdx.x; i < n4; i += stride) {
    float4 v = ((const float4*)X)[i];
    ((bf16x4*)Xb)[i] =
        (bf16x4){(bf16_t)v.x, (bf16_t)v.y, (bf16_t)v.z, (bf16_t)v.w};
  }
}

// ---------------------------------------------------------------------------
// FAST xg_gemm (round-5 verified): bf16 inputs, global_load_lds staging,
// 2x4 wave grid, XOR bank-swizzle both sides.
// ---------------------------------------------------------------------------
__global__ __launch_bounds__(512) void xg_gemm_fast(
    const bf16_t* __restrict__ Xb, const bf16_t* __restrict__ Wihb,
    const float* __restrict__ bias, bf16_t* __restrict__ xg2) {
  __shared__ __align__(16) bf16_t As[128][64];
  __shared__ __align__(16) bf16_t Bs[256][64];

  const int tid = threadIdx.x;
  const int lane = tid & 63;
  const int w = tid >> 6;
  const int wm = w >> 2;
  const int wn = w & 3;
  const int q = lane >> 4;
  const int l15 = lane & 15;
  const int m0 = blockIdx.x * 128;
  const int ch0 = blockIdx.y * 64;

  const int lr = lane >> 3;
  const int ls = (lane & 7) ^ (lr & 7);
  const int lc = ls * 8;

  f32x4 acc[4][4];
  #pragma unroll
  for (int mi = 0; mi < 4; ++mi)
    #pragma unroll
    for (int nf = 0; nf < 4; ++nf) acc[mi][nf] = (f32x4){0.f, 0.f, 0.f, 0.f};

  const char* As0 = (const char*)&As[0][0];
  const char* Bs0 = (const char*)&Bs[0][0];

  for (int kt = 0; kt < 8; ++kt) {
    const int k0 = kt * 64;
    __syncthreads();
    #pragma unroll
    for (int j = 0; j < 2; ++j) {
      const int c = w * 2 + j;
      gload_lds16(Xb + (size_t)(m0 + c * 8 + lr) * D_ + k0 + lc,
                  (char*)&As[0][0] + c * 1024);
    }
    #pragma unroll
    for (int j = 0; j < 4; ++j) {
      const int c = w * 4 + j;
      const int br = c * 8 + lr;
      const int wr = (br >> 6) * 256 + ch0 + (br & 63);
      gload_lds16(Wihb + (size_t)wr * D_ + k0 + lc,
                  (char*)&Bs[0][0] + c * 1024);
    }
    __syncthreads();
    #pragma unroll
    for (int kk = 0; kk < 2; ++kk) {
      bf16x8 a[4], b[4];
      #pragma unroll
      for (int mi = 0; mi < 4; ++mi) {
        const int row = wm * 64 + mi * 16 + l15;
        a[mi] = *(const bf16x8*)(As0 + row * 128 +
                                 (((kk * 4 + q) ^ (row & 7)) * 16));
      }
      #pragma unroll
      for (int nf = 0; nf < 4; ++nf) {
        const int row = nf * 64 + wn * 16 + l15;
        b[nf] = *(const bf16x8*)(Bs0 + row * 128 +
                                 (((kk * 4 + q) ^ (row & 7)) * 16));
      }
      #pragma unroll
      for (int mi = 0; mi < 4; ++mi)
        #pragma unroll
        for (int nf = 0; nf < 4; ++nf)
          acc[mi][nf] =
              __builtin_amdgcn_mfma_f32_16x16x32_bf16(a[mi], b[nf], acc[mi][nf], 0, 0, 0);
    }
  }
  const int cc = ch0 + wn * 16 + l15;
  const float bv0 = bias[cc], bv1 = bias[256 + cc];
  const float bv2 = bias[512 + cc], bv3 = bias[768 + cc];
  #pragma unroll
  for (int mi = 0; mi < 4; ++mi) {
    #pragma unroll
    for (int i = 0; i < 4; ++i) {
      const int row = m0 + wm * 64 + mi * 16 + 4 * q + i;
      bf16x4 v = (bf16x4){(bf16_t)(acc[mi][0][i] + bv0), (bf16_t)(acc[mi][1][i] + bv1),
                          (bf16_t)(acc[mi][2][i] + bv2), (bf16_t)(acc[mi][3][i] + bv3)};
      *(bf16x4*)(xg2 + ((size_t)row * 256 + cc) * 4) = v;
    }
  }
}

// ---------------------------------------------------------------------------
// SLOW xg_gemm (fallback): fp32 inputs, VALU staging.
// ---------------------------------------------------------------------------
__global__ __launch_bounds__(512) void xg_gemm(
    const float* __restrict__ X, const float* __restrict__ Wih,
    const float* __restrict__ bias, bf16_t* __restrict__ xg2) {
  __shared__ __align__(16) bf16_t As[128][72];
  __shared__ __align__(16) bf16_t Bs[256][72];

  const int tid = threadIdx.x;
  const int lane = tid & 63;
  const int w = tid >> 6;
  const int q = lane >> 4;
  const int l15 = lane & 15;
  const int m0 = blockIdx.x * 128;
  const int ch0 = blockIdx.y * 64;

  f32x4 acc[16];
  #pragma unroll
  for (int n = 0; n < 16; ++n) acc[n] = (f32x4){0.f, 0.f, 0.f, 0.f};

  for (int kt = 0; kt < 8; ++kt) {
    const int k0 = kt * 64;
    __syncthreads();
    #pragma unroll
    for (int i = 0; i < 4; ++i) {
      int f = tid + 512 * i;
      int r = f >> 4, c4 = f & 15;
      float4 va = *(const float4*)(X + (size_t)(m0 + r) * D_ + k0 + c4 * 4);
      *(bf16x4*)&As[r][c4 * 4] =
          (bf16x4){(bf16_t)va.x, (bf16_t)va.y, (bf16_t)va.z, (bf16_t)va.w};
    }
    #pragma unroll
    for (int j = 0; j < 8; ++j) {
      int f = tid + 512 * j;
      int r = f >> 4, c4 = f & 15;
      int wr = (r >> 6) * 256 + ch0 + (r & 63);
      float4 vb = *(const float4*)(Wih + (size_t)wr * D_ + k0 + c4 * 4);
      *(bf16x4*)&Bs[r][c4 * 4] =
          (bf16x4){(bf16_t)vb.x, (bf16_t)vb.y, (bf16_t)vb.z, (bf16_t)vb.w};
    }
    __syncthreads();
    #pragma unroll
    for (int kk = 0; kk < 2; ++kk) {
      bf16x8 a = *(const bf16x8*)&As[16 * w + l15][kk * 32 + q * 8];
      #pragma unroll
      for (int n = 0; n < 16; ++n) {
        bf16x8 b = *(const bf16x8*)&Bs[16 * n + l15][kk * 32 + q * 8];
        acc[n] = __builtin_amdgcn_mfma_f32_16x16x32_bf16(a, b, acc[n], 0, 0, 0);
      }
    }
  }
  #pragma unroll
  for (int cs = 0; cs < 4; ++cs) {
    const int cc = ch0 + cs * 16 + l15;
    float bv0 = bias[cc], bv1 = bias[256 + cc];
    float bv2 = bias[512 + cc], bv3 = bias[768 + cc];
    #pragma unroll
    for (int i = 0; i < 4; ++i) {
      int row = m0 + 16 * w + 4 * q + i;
      bf16x4 v = (bf16x4){(bf16_t)(acc[cs][i] + bv0), (bf16_t)(acc[4 + cs][i] + bv1),
                          (bf16_t)(acc[8 + cs][i] + bv2), (bf16_t)(acc[12 + cs][i] + bv3)};
      *(bf16x4*)(xg2 + ((size_t)row * 256 + cc) * 4) = v;
    }
  }
}

// ---------------------------------------------------------------------------
// NEW LSTM scan: 16 WGs x 1024 threads (16 waves). Wave w owns channels
// 16w..16w+15 for ALL 4 gates: weight slice = 4 n-tiles x 8 kk = 32 bf16x8
// frags = 128 VGPR -> the ENTIRE W_hh lives in registers (16 waves x 32 KB =
// 512 KB, zero duplication). No weight LDS at all; LDS = hbuf only (17 KB).
// vs old 8-wave scan: LDS-pipe work per step nearly halves (128 wlds reads
// gone), waves/SIMD doubles (2->4), shfl per wave halves.
// Fragment math = verified pattern: A row=l15 (batch), B row=N-col=l15
// (channel), C/D row=4q+i (batch) col=l15 (channel). Redistribution = old
// scan's lane^32 pull: lane (q,l15) ends with rows {rq, rq+1}, ch=16w+l15.
// ---------------------------------------------------------------------------
__global__ __launch_bounds__(1024) void lstm_scan16(
    const bf16_t* __restrict__ xg2, const bf16_t* __restrict__ whhb,
    float* __restrict__ hT) {
  __shared__ __align__(16) bf16_t hbuf[2][16][264];   // 16.9 KB

  const int tid = threadIdx.x;
  const int lane = tid & 63;
  const int w = tid >> 6;              // wave 0..15 -> channels 16w..16w+15
  const int q = lane >> 4;
  const int l15 = lane & 15;
  const int b0 = blockIdx.x * 8;
  const int ch = 16 * w + l15;
  const int rq = (q & 1) * 4 + (q >> 1) * 2;   // rows {rq, rq+1} after shfl
  const bool hi = (lane >= 32);

  // ---- W_hh -> registers: wf[g][kk], B-frag row = l15 -> Whh row g*256+ch
  bf16x8 wf[4][8];
  #pragma unroll
  for (int g = 0; g < 4; ++g)
    #pragma unroll
    for (int kk = 0; kk < 8; ++kk)
      wf[g][kk] = *(const bf16x8*)(whhb + ((size_t)g * 256 + ch) * 256 + kk * 32 + q * 8);

  for (int i = tid; i < 2 * 16 * 264; i += 1024) ((bf16_t*)hbuf)[i] = (bf16_t)0.0f;
  __syncthreads();

  float cst0 = 0.f, cst1 = 0.f;

  // xg: 4 gates packed bf16x4 at elem (row*256+ch)*4; rows rq, rq+1
  const bf16_t* xp0 = xg2 + (size_t)(b0 + rq) * T_ * 1024 + ch * 4;
  const bf16_t* xp1 = xg2 + (size_t)(b0 + rq + 1) * T_ * 1024 + ch * 4;
  bf16x4 xv0 = *(const bf16x4*)xp0, xv1 = *(const bf16x4*)xp1;   // t=0
  xp0 += 1024; xp1 += 1024;

  #pragma unroll 1
  for (int t = 0; t < T_; ++t) {
    // prefetch t+1 (in flight across this step's barrier; t=1023 overrun
    // lands in whhb region, read-only + unused)
    bf16x4 xn0 = *(const bf16x4*)xp0;
    bf16x4 xn1 = *(const bf16x4*)xp1;
    xp0 += 1024; xp1 += 1024;
    const int cur = t & 1;

    // ---- gates = h @ Whh^T for this wave's 16 channels x 4 gates ----
    f32x4 acc[4];
    #pragma unroll
    for (int g = 0; g < 4; ++g) acc[g] = (f32x4){0.f, 0.f, 0.f, 0.f};
    #pragma unroll
    for (int kk = 0; kk < 8; ++kk) {
      bf16x8 a = *(const bf16x8*)&hbuf[cur][l15][kk * 32 + q * 8];
      acc[0] = __builtin_amdgcn_mfma_f32_16x16x32_bf16(a, wf[0][kk], acc[0], 0, 0, 0);
      acc[1] = __builtin_amdgcn_mfma_f32_16x16x32_bf16(a, wf[1][kk], acc[1], 0, 0, 0);
      acc[2] = __builtin_amdgcn_mfma_f32_16x16x32_bf16(a, wf[2][kk], acc[2], 0, 0, 0);
      acc[3] = __builtin_amdgcn_mfma_f32_16x16x32_bf16(a, wf[3][kk], acc[3], 0, 0, 0);
    }

    // ---- redistribute: lane ends with rows rq, rq+1 (verified pattern) ----
    float G0[4], G1[4];
    #pragma unroll
    for (int g = 0; g < 4; ++g) {
      float s2 = __shfl(acc[g][2], lane ^ 32, 64);
      float s3 = __shfl(acc[g][3], lane ^ 32, 64);
      G0[g] = hi ? s2 : acc[g][0];
      G1[g] = hi ? s3 : acc[g][1];
    }

    // ---- 2 cell updates (rows b0+rq, b0+rq+1; channel ch) ----
    float gi0 = G0[0] + (float)xv0[0], gf0 = G0[1] + (float)xv0[1];
    float gg0 = G0[2] + (float)xv0[2], go0 = G0[3] + (float)xv0[3];
    float I0 = sigmoid_f(gi0), F0 = sigmoid_f(gf0);
    float Gg0 = tanh_f(gg0), O0 = sigmoid_f(go0);
    float cv0 = F0 * cst0 + I0 * Gg0; cst0 = cv0;
    float hv0 = O0 * tanh_f(cv0);

    float gi1 = G1[0] + (float)xv1[0], gf1 = G1[1] + (float)xv1[1];
    float gg1 = G1[2] + (float)xv1[2], go1 = G1[3] + (float)xv1[3];
    float I1 = sigmoid_f(gi1), F1 = sigmoid_f(gf1);
    float Gg1 = tanh_f(gg1), O1 = sigmoid_f(go1);
    float cv1 = F1 * cst1 + I1 * Gg1; cst1 = cv1;
    float hv1 = O1 * tanh_f(cv1);

    hbuf[cur ^ 1][rq][ch]     = (bf16_t)hv0;
    hbuf[cur ^ 1][rq + 1][ch] = (bf16_t)hv1;

    if (t == T_ - 1) {
      hT[(size_t)(b0 + rq) * H_ + ch]     = hv0;
      hT[(size_t)(b0 + rq + 1) * H_ + ch] = hv1;
    }

    xv0 = xn0; xv1 = xn1;
    barrier_lds_only();
  }
}

// ---------------------------------------------------------------------------
// OLD LSTM scan (fallback, verified): 16 WGs x 8 batch rows, 8 waves/WG.
// ---------------------------------------------------------------------------
__global__ __launch_bounds__(512, 2) void lstm_scan(
    const bf16_t* __restrict__ xg2, const bf16_t* __restrict__ Whh,
    float* __restrict__ hT) {
  __shared__ __align__(16) bf16_t wlds[8 * 16 * 512];   // 128 KB
  __shared__ __align__(16) bf16_t hbuf[2][16][264];     // 16.9 KB

  const int tid = threadIdx.x;
  const int lane = tid & 63;
  const int w = tid >> 6;
  const int q = lane >> 4;
  const int l15 = lane & 15;
  const int b0 = blockIdx.x * 8;
  const int rq = (q & 1) * 4 + (q >> 1) * 2;
  const bool hi = (lane >= 32);

  bf16x8 wreg[6][8];
  #pragma unroll
  for (int p2 = 0; p2 < 2; ++p2) {
    #pragma unroll
    for (int g2 = 0; g2 < 4; ++g2) {
      const int j = p2 * 4 + g2;
      const bf16_t* src =
          Whh + (size_t)(g2 * 256 + 32 * w + 16 * p2 + l15) * H_ + q * 8;
      #pragma unroll
      for (int kk = 0; kk < 8; ++kk) {
        bf16x8 v = *(const bf16x8*)(src + kk * 32);
        if (j < 6) {
          wreg[j][kk] = v;
        } else {
          *(bf16x8*)&wlds[(size_t)((w * 16 + (g2 - 2) * 8 + kk)) * 512 + lane * 8] = v;
        }
      }
    }
  }

  for (int i = tid; i < 2 * 16 * 264; i += 512) ((bf16_t*)hbuf)[i] = (bf16_t)0.0f;
  __syncthreads();

  float cst[2][2];
  #pragma unroll
  for (int p = 0; p < 2; ++p) { cst[p][0] = 0.f; cst[p][1] = 0.f; }

  const bf16_t* xp[2][2];
  #pragma unroll
  for (int p = 0; p < 2; ++p)
    #pragma unroll
    for (int k = 0; k < 2; ++k)
      xp[p][k] = xg2 + (size_t)(b0 + rq + k) * (size_t)T_ * 1024 + (32 * w + 16 * p + l15) * 4;

  bf16x4 xv[2][2], xn[2][2];
  #pragma unroll
  for (int p = 0; p < 2; ++p)
    #pragma unroll
    for (int k = 0; k < 2; ++k) {
      xv[p][k] = *(const bf16x4*)xp[p][k];
      xp[p][k] += 1024;
    }

  auto step = [&](int t, bf16x4 (&xc)[2][2], bf16x4 (&xf)[2][2]) {
    #pragma unroll
    for (int p = 0; p < 2; ++p)
      #pragma unroll
      for (int k = 0; k < 2; ++k) {
        xf[p][k] = *(const bf16x4*)xp[p][k];
        xp[p][k] += 1024;
      }
    const int cur = t & 1;
    #pragma unroll
    for (int p = 0; p < 2; ++p) {
      f32x4 acc[4];
      #pragma unroll
      for (int g = 0; g < 4; ++g) acc[g] = (f32x4){0.f, 0.f, 0.f, 0.f};
      #pragma unroll
      for (int kk = 0; kk < 8; ++kk) {
        bf16x8 a = *(const bf16x8*)&hbuf[cur][l15][kk * 32 + q * 8];
        if (p == 0) {
          acc[0] = __builtin_amdgcn_mfma_f32_16x16x32_bf16(a, wreg[0][kk], acc[0], 0, 0, 0);
          acc[1] = __builtin_amdgcn_mfma_f32_16x16x32_bf16(a, wreg[1][kk], acc[1], 0, 0, 0);
          acc[2] = __builtin_amdgcn_mfma_f32_16x16x32_bf16(a, wreg[2][kk], acc[2], 0, 0, 0);
          acc[3] = __builtin_amdgcn_mfma_f32_16x16x32_bf16(a, wreg[3][kk], acc[3], 0, 0, 0);
        } else {
          acc[0] = __builtin_amdgcn_mfma_f32_16x16x32_bf16(a, wreg[4][kk], acc[0], 0, 0, 0);
          acc[1] = __builtin_amdgcn_mfma_f32_16x16x32_bf16(a, wreg[5][kk], acc[1], 0, 0, 0);
          bf16x8 bg = *(const bf16x8*)&wlds[(size_t)(w * 16 + kk) * 512 + lane * 8];
          bf16x8 bo = *(const bf16x8*)&wlds[(size_t)(w * 16 + 8 + kk) * 512 + lane * 8];
          acc[2] = __builtin_amdgcn_mfma_f32_16x16x32_bf16(a, bg, acc[2], 0, 0, 0);
          acc[3] = __builtin_amdgcn_mfma_f32_16x16x32_bf16(a, bo, acc[3], 0, 0, 0);
        }
      }
      float G0[4], G1[4];
      #pragma unroll
      for (int g = 0; g < 4; ++g) {
        float s2 = __shfl(acc[g][2], lane ^ 32, 64);
        float s3 = __shfl(acc[g][3], lane ^ 32, 64);
        G0[g] = hi ? s2 : acc[g][0];
        G1[g] = hi ? s3 : acc[g][1];
      }
      const int c = 32 * w + 16 * p + l15;
      #pragma unroll
      for (int k = 0; k < 2; ++k) {
        const float* Gv_ = k ? G1 : G0;
        float gi = Gv_[0] + (float)xc[p][k][0];
        float gf = Gv_[1] + (float)xc[p][k][1];
        float gg = Gv_[2] + (float)xc[p][k][2];
        float go = Gv_[3] + (float)xc[p][k][3];
        float I = sigmoid_f(gi);
        float F = sigmoid_f(gf);
        float Gg = tanh_f(gg);
        float Ov = sigmoid_f(go);
        float cv = F * cst[p][k] + I * Gg;
        cst[p][k] = cv;
        float hv = Ov * tanh_f(cv);
        hbuf[cur ^ 1][rq + k][c] = (bf16_t)hv;
        if (t == T_ - 1) hT[(size_t)(b0 + rq + k) * H_ + c] = hv;
      }
    }
    barrier_lds_only();
  };

  #pragma unroll 1
  for (int t = 0; t < T_; t += 2) {
    step(t, xv, xn);
    step(t + 1, xn, xv);
  }
}

// ---------------------------------------------------------------------------
// out = h_T @ W_out^T + b_out
// ---------------------------------------------------------------------------
__global__ __launch_bounds__(128) void head_gemm(
    const float* __restrict__ hT, const float* __restrict__ Wout,
    const float* __restrict__ bout, float* __restrict__ out) {
  __shared__ float hrow[H_];
  const int b = blockIdx.x;
  const int o = threadIdx.x;
  hrow[o] = hT[(size_t)b * H_ + o];
  hrow[o + 128] = hT[(size_t)b * H_ + 128 + o];
  __syncthreads();
  float s = bout[o];
  const float* wr = Wout + (size_t)o * H_;
  #pragma unroll 8
  for (int j = 0; j < H_; ++j) s += hrow[j] * wr[j];
  out[(size_t)b * 128 + o] = s;
}

// ---------------------------------------------------------------------------
extern "C" void kernel_launch(void* const* d_in, const int* in_sizes, int n_in,
                              void* d_out, int out_size, void* d_ws, size_t ws_size,
                              hipStream_t stream) {
  const float* X    = (const float*)d_in[0];
  const float* Wih  = (const float*)d_in[1];
  const float* Whh  = (const float*)d_in[2];
  const float* bih  = (const float*)d_in[3];
  const float* bhh  = (const float*)d_in[4];
  const float* Wout = (const float*)d_in[5];
  const float* bout = (const float*)d_in[6];
  float* out = (float*)d_out;

  // workspace layout (bytes). Prefix byte-identical to the proven layout;
  // wihb/xb exist only on the fast path, gated on ws_size.
  char* ws = (char*)d_ws;
  const size_t XG_BYTES   = (size_t)B_ * T_ * G_ * 2;   // 268435456
  const size_t WHHB_BYTES = (size_t)G_ * H_ * 2;        // 524288
  const size_t BIAS_BYTES = (size_t)G_ * 4;             // 4096
  const size_t HT_BYTES   = (size_t)B_ * H_ * 4;        // 131072
  const size_t WIHB_BYTES = (size_t)G_ * D_ * 2;        // 1048576
  const size_t XB_BYTES   = (size_t)B_ * T_ * D_ * 2;   // 134217728
  bf16_t* xg2  = (bf16_t*)ws;
  bf16_t* whhb = (bf16_t*)(ws + XG_BYTES);
  float*  bias = (float*)(ws + XG_BYTES + WHHB_BYTES);
  float*  hT   = (float*)(ws + XG_BYTES + WHHB_BYTES + BIAS_BYTES);
  bf16_t* wihb = (bf16_t*)(ws + XG_BYTES + WHHB_BYTES + BIAS_BYTES + HT_BYTES);
  bf16_t* xb   = (bf16_t*)(ws + XG_BYTES + WHHB_BYTES + BIAS_BYTES + HT_BYTES + WIHB_BYTES);

  const size_t NEED_FAST =
      XG_BYTES + WHHB_BYTES + BIAS_BYTES + HT_BYTES + WIHB_BYTES + XB_BYTES;

  if (ws_size >= NEED_FAST) {
    prep_full_kernel<<<dim3(2048), 256, 0, stream>>>(Whh, bih, bhh, Wih, whhb, wihb, bias);
    xconv_kernel<<<dim3(4096), 256, 0, stream>>>(X, xb);
    xg_gemm_fast<<<dim3((B_ * T_) / 128, 4), 512, 0, stream>>>(xb, wihb, bias, xg2);
    lstm_scan16<<<dim3(B_ / 8), 1024, 0, stream>>>(xg2, whhb, hT);
  } else {
    prep_kernel<<<dim3(1024), 256, 0, stream>>>(Whh, bih, bhh, whhb, bias);
    xg_gemm<<<dim3((B_ * T_) / 128, 4), 512, 0, stream>>>(X, Wih, bias, xg2);
    lstm_scan<<<dim3(B_ / 8), 512, 0, stream>>>(xg2, whhb, hT);
  }
  head_gemm<<<dim3(B_), 128, 0, stream>>>(hT, Wout, bout, out);
}